// Round 9
// baseline (336.066 us; speedup 1.0000x reference)
//
#include <hip/hip_runtime.h>
#include <hip/hip_bf16.h>
#include <cstdint>
#include <cstddef>

#define T_TOK 2048
#define HDIM  1024
#define FDIM  2048
#define NEXP  8

typedef __attribute__((ext_vector_type(8))) short bf16x8;
typedef __attribute__((ext_vector_type(4))) float f32x4;

__device__ __forceinline__ unsigned short f2b(float f) {
  __hip_bfloat16 h = __float2bfloat16(f);
  return __builtin_bit_cast(unsigned short, h);
}

__device__ __forceinline__ void gload16(const void* g, void* l) {
  __builtin_amdgcn_global_load_lds(
      (const __attribute__((address_space(1))) unsigned int*)g,
      (__attribute__((address_space(3))) unsigned int*)l, 16, 0, 0);
}

// two f32x4 (LDS half-chunks) -> bf16x8 fragment (v_cvt_pk_bf16_f32 x4)
__device__ __forceinline__ bf16x8 cvt_frag(f32x4 lo, f32x4 hi) {
  union { unsigned short u[8]; bf16x8 v; } r;
  r.u[0] = f2b(lo[0]); r.u[1] = f2b(lo[1]); r.u[2] = f2b(lo[2]); r.u[3] = f2b(lo[3]);
  r.u[4] = f2b(hi[0]); r.u[5] = f2b(hi[1]); r.u[6] = f2b(hi[2]); r.u[7] = f2b(hi[3]);
  return r.v;
}

// ---------------- router + sparsemixer (eval) + x->bf16 ----------------
__global__ __launch_bounds__(256) void router_k(
    const float* __restrict__ x, const float* __restrict__ rw,
    float* __restrict__ wslot, int* __restrict__ rows,
    int* __restrict__ cnt, unsigned short* __restrict__ xb)
{
  const int wave = threadIdx.x >> 6, lane = threadIdx.x & 63;
  const int t = blockIdx.x * 4 + wave;
  const float* xr = x + (size_t)t * HDIM;
  unsigned short* xbr = xb + (size_t)t * HDIM;
  float acc[NEXP];
#pragma unroll
  for (int e = 0; e < NEXP; ++e) acc[e] = 0.f;
  for (int i = 0; i < HDIM / 64; ++i) {
    const int h = i * 64 + lane;
    const float xv = xr[h];
    xbr[h] = f2b(xv);
#pragma unroll
    for (int e = 0; e < NEXP; ++e) acc[e] += xv * rw[e * HDIM + h];
  }
#pragma unroll
  for (int e = 0; e < NEXP; ++e) {
#pragma unroll
    for (int off = 32; off; off >>= 1) acc[e] += __shfl_xor(acc[e], off);
  }
  if (lane == 0) {
    float m1 = acc[0]; int i1 = 0;
#pragma unroll
    for (int e = 1; e < NEXP; ++e) if (acc[e] > m1) { m1 = acc[e]; i1 = e; }
    float sum1 = 0.f;
#pragma unroll
    for (int e = 0; e < NEXP; ++e) {
      const float f = fmaxf(fabsf(acc[e]), m1);
      if (m1 - acc[e] <= 0.02f * f) sum1 += expf(acc[e] - m1);
    }
    float m2 = -3.4e38f; int i2 = 0;
#pragma unroll
    for (int e = 0; e < NEXP; ++e)
      if (e != i1 && acc[e] > m2) { m2 = acc[e]; i2 = e; }
    float sum2 = 0.f;
#pragma unroll
    for (int e = 0; e < NEXP; ++e) {
      if (e == i1) continue;
      const float f = fmaxf(fabsf(acc[e]), m2);
      if (m2 - acc[e] <= 0.02f * f) sum2 += expf(acc[e] - m2);
    }
    wslot[2 * t]     = 1.f / sum1;
    wslot[2 * t + 1] = 1.f / sum2;
    int p1 = atomicAdd(&cnt[i1], 1); rows[i1 * T_TOK + p1] = 2 * t;
    int p2 = atomicAdd(&cnt[i2], 1); rows[i2 * T_TOK + p2] = 2 * t + 1;
  }
}

// ---------------- gate/up GEMM: 256x64x32, 512 thr, fp32-direct B ----------------
// A: 16 bf16 chunks (16r x 32k, lane-linear 16B). Bg/Bu: 4 fp32 chunks, each as
// two half-chunks (half h: floats h*4..h*4+3 of every lane slot) -- HW-native.
// Wave grid 4x2: wave = 64 rows x 32 cols; per wave mf=4, nf=2, dual (g,u) acc.
__global__ __launch_bounds__(512) void gemm_gateup_k(
    const unsigned short* __restrict__ xb,
    const float* __restrict__ wg32, const float* __restrict__ wu32,
    const int* __restrict__ rows, const int* __restrict__ cnt,
    const float* __restrict__ wslot, unsigned short* __restrict__ hbuf)
{
  const int bx = blockIdx.x;
  const int e  = bx >> 8;           // 8 mt x 32 nt = 256
  const int mt = (bx >> 5) & 7;
  const int nt = bx & 31;
  const int cnt_e = cnt[e];
  if (mt * 256 >= cnt_e) return;

  __shared__ unsigned short As[8192];   // 16 chunks x 512 bf16 = 16 KiB
  __shared__ float Bg[2048];            // 4 chunks x (2 x 256 fp32) = 8 KiB
  __shared__ float Bu[2048];
  __shared__ int ldsRow[256];

  const int tid = threadIdx.x;
  if (tid < 256) {
    const int idx = mt * 256 + tid;
    ldsRow[tid] = (idx < cnt_e) ? rows[e * T_TOK + idx] : -1;
  }
  __syncthreads();

  const int lane = tid & 63, w = tid >> 6;     // 8 waves
  const int wr = w >> 1, wc = w & 1;           // 4x2 grid
  const int lr = lane & 15, lq = lane >> 4;

  // A staging: chunks c = w + 8*it (it 0..1); chunk c covers rows c*16..+16
  const unsigned short* aS[2];
  int aOff[2];
#pragma unroll
  for (int it = 0; it < 2; ++it) {
    const int c = w + 8 * it;
    int r = ldsRow[c * 16 + lr]; if (r < 0) r = 0;
    aS[it] = xb + (size_t)(r >> 1) * HDIM + lq * 8;
    aOff[it] = c * 512 + lane * 8;
  }
  // B staging: wave w stages half (w&1) of chunk (w>>1) for both Bg and Bu
  const int bc = w >> 1, bh = w & 1;
  const float* gS = wg32 + ((size_t)e * FDIM + nt * 64 + bc * 16 + lr) * HDIM + lq * 8 + bh * 4;
  const float* uS = wu32 + ((size_t)e * FDIM + nt * 64 + bc * 16 + lr) * HDIM + lq * 8 + bh * 4;
  const int bOff = bc * 512 + bh * 256 + lane * 4;

  f32x4 accg[4][2], accu[4][2];
#pragma unroll
  for (int mf = 0; mf < 4; ++mf)
#pragma unroll
    for (int nf = 0; nf < 2; ++nf) {
      accg[mf][nf] = (f32x4){0.f, 0.f, 0.f, 0.f};
      accu[mf][nf] = (f32x4){0.f, 0.f, 0.f, 0.f};
    }

  for (int k = 0; k < 32; ++k) {        // K = 1024, BK = 32
    const int ko = k * 32;
    gload16(aS[0] + ko, &As[aOff[0]]);
    gload16(aS[1] + ko, &As[aOff[1]]);
    gload16(gS + ko, &Bg[bOff]);
    gload16(uS + ko, &Bu[bOff]);
    __syncthreads();                    // drain vmcnt: tile staged

    bf16x8 a[4], bg[2], bu[2];
#pragma unroll
    for (int mf = 0; mf < 4; ++mf)
      a[mf] = *(const bf16x8*)&As[(wr * 4 + mf) * 512 + lane * 8];
#pragma unroll
    for (int nf = 0; nf < 2; ++nf) {
      const int c = wc * 2 + nf;
      bg[nf] = cvt_frag(*(const f32x4*)&Bg[c * 512 + lane * 4],
                        *(const f32x4*)&Bg[c * 512 + 256 + lane * 4]);
      bu[nf] = cvt_frag(*(const f32x4*)&Bu[c * 512 + lane * 4],
                        *(const f32x4*)&Bu[c * 512 + 256 + lane * 4]);
    }
#pragma unroll
    for (int mf = 0; mf < 4; ++mf)
#pragma unroll
      for (int nf = 0; nf < 2; ++nf) {
        accg[mf][nf] = __builtin_amdgcn_mfma_f32_16x16x32_bf16(a[mf], bg[nf], accg[mf][nf], 0, 0, 0);
        accu[mf][nf] = __builtin_amdgcn_mfma_f32_16x16x32_bf16(a[mf], bu[nf], accu[mf][nf], 0, 0, 0);
      }
    __syncthreads();                    // protect LDS before restage
  }

  // epilogue: h = silu(g)*u*w   (C/D: col=lane&15, row=(lane>>4)*4+i)
#pragma unroll
  for (int mf = 0; mf < 4; ++mf)
#pragma unroll
    for (int nf = 0; nf < 2; ++nf) {
      const int col = nt * 64 + wc * 32 + nf * 16 + lr;
#pragma unroll
      for (int i = 0; i < 4; ++i) {
        const int lrow = wr * 64 + mf * 16 + lq * 4 + i;
        const int r = ldsRow[lrow];
        if (r < 0) continue;
        const float g = accg[mf][nf][i], u = accu[mf][nf][i];
        const float val = g / (1.f + __expf(-g)) * u * wslot[r];
        hbuf[(size_t)r * FDIM + col] = f2b(val);
      }
    }
}

// ---------------- down GEMM: 256x64x64, 512 thr, fp32-direct B, plain stores ----
// A: 32 bf16 chunks (c = rb*2+kk). B: 8 fp32 chunks (c = cb*2+kk), half-chunked.
__global__ __launch_bounds__(512) void gemm_down_k(
    const unsigned short* __restrict__ hbuf,
    const float* __restrict__ wd32,
    const int* __restrict__ rows, const int* __restrict__ cnt,
    float* __restrict__ obuf)
{
  const int bx = blockIdx.x;
  const int e  = bx >> 7;           // 8 mt x 16 nt = 128
  const int mt = (bx >> 4) & 7;
  const int nt = bx & 15;
  const int cnt_e = cnt[e];
  if (mt * 256 >= cnt_e) return;

  __shared__ unsigned short As[16384];  // 32 chunks x 512 bf16 = 32 KiB
  __shared__ float Bs[4096];            // 8 chunks x (2 x 256 fp32) = 16 KiB
  __shared__ int ldsRow[256];

  const int tid = threadIdx.x;
  if (tid < 256) {
    const int idx = mt * 256 + tid;
    ldsRow[tid] = (idx < cnt_e) ? rows[e * T_TOK + idx] : -1;
  }
  __syncthreads();

  const int lane = tid & 63, w = tid >> 6;
  const int wr = w >> 1, wc = w & 1;    // 4x2 grid: wave = 64 rows x 32 cols
  const int lr = lane & 15, lq = lane >> 4;

  // A staging: chunks c = w + 8*it (it 0..3); c = rb*2+kk
  const unsigned short* aS[4];
  int aOff[4];
#pragma unroll
  for (int it = 0; it < 4; ++it) {
    const int c = w + 8 * it;
    const int rb = c >> 1, kk = c & 1;
    int r = ldsRow[rb * 16 + lr]; if (r < 0) r = 0;
    aS[it] = hbuf + (size_t)r * FDIM + kk * 32 + lq * 8;
    aOff[it] = c * 512 + lane * 8;
  }
  // B staging: tasks t = w + 8*j (j 0..1): chunk c = t>>1, half h = t&1; c = cb*2+kk
  const float* bS[2];
  int bOff[2];
#pragma unroll
  for (int j = 0; j < 2; ++j) {
    const int t = w + 8 * j;
    const int c = t >> 1, h = t & 1;
    const int cb = c >> 1, kk = c & 1;
    bS[j] = wd32 + ((size_t)e * HDIM + nt * 64 + cb * 16 + lr) * FDIM + kk * 32 + lq * 8 + h * 4;
    bOff[j] = c * 512 + h * 256 + lane * 4;
  }

  f32x4 acc[4][2];
#pragma unroll
  for (int mf = 0; mf < 4; ++mf)
#pragma unroll
    for (int nf = 0; nf < 2; ++nf) acc[mf][nf] = (f32x4){0.f, 0.f, 0.f, 0.f};

  for (int k = 0; k < 32; ++k) {        // K = 2048, BK = 64
    const int ko = k * 64;
    gload16(aS[0] + ko, &As[aOff[0]]);
    gload16(aS[1] + ko, &As[aOff[1]]);
    gload16(aS[2] + ko, &As[aOff[2]]);
    gload16(aS[3] + ko, &As[aOff[3]]);
    gload16(bS[0] + ko, &Bs[bOff[0]]);
    gload16(bS[1] + ko, &Bs[bOff[1]]);
    __syncthreads();

    bf16x8 a[4][2], b[2][2];
#pragma unroll
    for (int mf = 0; mf < 4; ++mf)
#pragma unroll
      for (int kk = 0; kk < 2; ++kk)
        a[mf][kk] = *(const bf16x8*)&As[((wr * 4 + mf) * 2 + kk) * 512 + lane * 8];
#pragma unroll
    for (int nf = 0; nf < 2; ++nf)
#pragma unroll
      for (int kk = 0; kk < 2; ++kk) {
        const int c = (wc * 2 + nf) * 2 + kk;
        b[nf][kk] = cvt_frag(*(const f32x4*)&Bs[c * 512 + lane * 4],
                             *(const f32x4*)&Bs[c * 512 + 256 + lane * 4]);
      }
#pragma unroll
    for (int mf = 0; mf < 4; ++mf)
#pragma unroll
      for (int nf = 0; nf < 2; ++nf)
#pragma unroll
        for (int kk = 0; kk < 2; ++kk)
          acc[mf][nf] = __builtin_amdgcn_mfma_f32_16x16x32_bf16(a[mf][kk], b[nf][kk], acc[mf][nf], 0, 0, 0);
    __syncthreads();
  }

#pragma unroll
  for (int mf = 0; mf < 4; ++mf)
#pragma unroll
    for (int nf = 0; nf < 2; ++nf) {
      const int col = nt * 64 + wc * 32 + nf * 16 + lr;
#pragma unroll
      for (int i = 0; i < 4; ++i) {
        const int lrow = wr * 64 + mf * 16 + lq * 4 + i;
        const int r = ldsRow[lrow];
        if (r < 0) continue;
        obuf[(size_t)r * HDIM + col] = acc[mf][nf][i];
      }
    }
}

// ---------------- combine: out[t] = obuf[2t] + obuf[2t+1] ----------------
__global__ __launch_bounds__(256) void combine_k(const float* __restrict__ obuf,
                                                 float* __restrict__ out)
{
  const int i = blockIdx.x * 256 + threadIdx.x;
  const int t = i >> 8, c = i & 255;
  const float4* o4 = (const float4*)obuf;
  const float4 a = o4[(size_t)(2 * t) * (HDIM / 4) + c];
  const float4 b = o4[(size_t)(2 * t + 1) * (HDIM / 4) + c];
  float4 r; r.x = a.x + b.x; r.y = a.y + b.y; r.z = a.z + b.z; r.w = a.w + b.w;
  ((float4*)out)[i] = r;
}

extern "C" void kernel_launch(void* const* d_in, const int* in_sizes, int n_in,
                              void* d_out, int out_size, void* d_ws, size_t ws_size,
                              hipStream_t stream) {
  const float* x  = (const float*)d_in[0];
  const float* rw = (const float*)d_in[1];
  const float* wg = (const float*)d_in[2];
  const float* wu = (const float*)d_in[3];
  const float* wd = (const float*)d_in[4];
  float* out = (float*)d_out;

  char* ws = (char*)d_ws;
  unsigned short* hbuf = (unsigned short*)ws;                        // 16 MiB
  unsigned short* xb   = (unsigned short*)(ws + (16u << 20));        // 4 MiB
  int*   cnt   = (int*)  (ws + (20u << 20));                         // 256 B
  int*   rows  = (int*)  (ws + (20u << 20) + 256);                   // 64 KiB
  float* wslot = (float*)(ws + (20u << 20) + 256 + 65536);           // 16 KiB
  float* obuf  = (float*)(ws + (24ull << 20));                       // 16 MiB

  hipMemsetAsync(cnt, 0, 256, stream);
  router_k<<<T_TOK / 4, 256, 0, stream>>>(x, rw, wslot, rows, cnt, xb);
  gemm_gateup_k<<<NEXP * 8 * 32, 512, 0, stream>>>(xb, wg, wu, rows, cnt, wslot, hbuf);
  gemm_down_k<<<NEXP * 8 * 16, 512, 0, stream>>>(hbuf, wd, rows, cnt, obuf);
  combine_k<<<T_TOK * HDIM / 4 / 256, 256, 0, stream>>>(obuf, out);
}